// Round 3
// baseline (869.240 us; speedup 1.0000x reference)
//
#include <hip/hip_runtime.h>
#include <hip/hip_bf16.h>

#define N_NODES 100000
#define N_EDGES 3200000

// ---------------- edge_index dtype detect + normalize ----------------
// Handles either int64 or int32 upload of edge_index. For int64 data
// (values < 2^31), int32-view odd words are all zero; genuine int32 data has
// random row indices there. Graph-capture safe: same work every call.

__global__ void k_detect(const unsigned* __restrict__ w, int* __restrict__ flag) {
    __shared__ unsigned s[256];
    unsigned v = 0;
    for (int t = threadIdx.x; t < 4096; t += 256) v |= w[2 * t + 1];
    s[threadIdx.x] = v;
    __syncthreads();
    for (int off = 128; off > 0; off >>= 1) {
        if (threadIdx.x < (unsigned)off) s[threadIdx.x] |= s[threadIdx.x + off];
        __syncthreads();
    }
    if (threadIdx.x == 0) flag[0] = (s[0] == 0) ? 1 : 0;  // 1 => int64 layout
}

__global__ void k_convert(const unsigned* __restrict__ w, const int* __restrict__ flag,
                          int* __restrict__ row, int* __restrict__ col, int E) {
    int e = blockIdx.x * blockDim.x + threadIdx.x;
    if (e < E) {
        if (flag[0]) {  // int64: row[e] low word at 2e; col[e] low word at 2E+2e
            row[e] = (int)w[2 * e];
            col[e] = (int)w[2 * E + 2 * e];
        } else {        // int32
            row[e] = (int)w[e];
            col[e] = (int)w[E + e];
        }
    }
}

// ---------------- degree / norm ----------------

__global__ void k_deg_init(float* __restrict__ deg, int n) {
    int i = blockIdx.x * blockDim.x + threadIdx.x;
    if (i < n) deg[i] = 1.0f;  // self-loop weight
}

__global__ void k_deg_accum(const int* __restrict__ col, const float* __restrict__ w,
                            float* __restrict__ deg, int E, int n) {
    int e = blockIdx.x * blockDim.x + threadIdx.x;
    if (e < E) {
        int c = col[e];
        if ((unsigned)c < (unsigned)n) atomicAdd(&deg[c], w[e]);
    }
}

__global__ void k_dinv(float* __restrict__ deg, int n) {
    int i = blockIdx.x * blockDim.x + threadIdx.x;
    if (i < n) {
        float d = deg[i];
        deg[i] = d > 0.f ? 1.0f / sqrtf(d) : 0.f;
    }
}

// ---------------- layer 1: g1 = dinv * (x @ W1) ----------------
// block = 256 threads = 8 nodes x 32 out-channels. W1 (128x32) in LDS.

__global__ __launch_bounds__(256) void k_gemm1(const float* __restrict__ x,
                                               const float* __restrict__ W1,
                                               const float* __restrict__ dinv,
                                               float* __restrict__ g1, int n) {
    __shared__ float W1s[128 * 32];
    __shared__ float xs[8][128];
    int tid = threadIdx.x;
    for (int i = tid; i < 128 * 32; i += 256) W1s[i] = W1[i];
    int node0 = blockIdx.x * 8;
    for (int i = tid; i < 8 * 128; i += 256) {
        int ln = i >> 7, ii = i & 127;
        int node = node0 + ln;
        xs[ln][ii] = (node < n) ? x[node * 128 + ii] : 0.f;
    }
    __syncthreads();
    int ln = tid >> 5;   // 0..7
    int kk = tid & 31;   // 0..31
    int node = node0 + ln;
    if (node < n) {
        float acc = 0.f;
#pragma unroll
        for (int i = 0; i < 128; ++i) acc += xs[ln][i] * W1s[i * 32 + kk];
        g1[node * 32 + kk] = dinv[node] * acc;
    }
}

// ---------------- scatter layer 1: 32 lanes per edge ----------------

__global__ __launch_bounds__(256) void k_scatter1(const int* __restrict__ row,
                                                  const int* __restrict__ col,
                                                  const float* __restrict__ w,
                                                  const float* __restrict__ g1,
                                                  float* __restrict__ acc1, int E, int n) {
    long long t = (long long)blockIdx.x * 256 + threadIdx.x;
    int e = (int)(t >> 5);
    int k = (int)(t & 31);
    if (e < E) {
        int r = row[e], c = col[e];
        if ((unsigned)r < (unsigned)n && (unsigned)c < (unsigned)n) {
            float v = g1[r * 32 + k] * w[e];
            atomicAdd(&acc1[c * 32 + k], v);
        }
    }
}

// epilogue 1: h1 = leaky(dinv*(acc1 + g1) + b1), written in-place into acc1
__global__ void k_post1(const float* __restrict__ g1, const float* __restrict__ dinv,
                        const float* __restrict__ b1, float* __restrict__ acc1, int n) {
    int t = blockIdx.x * blockDim.x + threadIdx.x;
    if (t < n * 32) {
        int node = t >> 5, k = t & 31;
        float v = dinv[node] * (acc1[t] + g1[t]) + b1[k];
        acc1[t] = v > 0.f ? v : 0.01f * v;
    }
}

// ---------------- layer 2: g2 = dinv * (h1 @ W2) ----------------

__global__ __launch_bounds__(256) void k_gemm2(const float* __restrict__ h1,
                                               const float* __restrict__ W2,
                                               const float* __restrict__ dinv,
                                               float* __restrict__ g2, int n) {
    __shared__ float W2s[32 * 16];
    int tid = threadIdx.x;
    for (int i = tid; i < 32 * 16; i += 256) W2s[i] = W2[i];  // FIX: full 512 floats
    __syncthreads();
    int t = blockIdx.x * 256 + tid;
    if (t < n * 16) {
        int node = t >> 4, j = t & 15;
        float acc = 0.f;
#pragma unroll
        for (int k = 0; k < 32; ++k) acc += h1[node * 32 + k] * W2s[k * 16 + j];
        g2[t] = dinv[node] * acc;
    }
}

// ---------------- scatter layer 2: 16 lanes per edge ----------------

__global__ __launch_bounds__(256) void k_scatter2(const int* __restrict__ row,
                                                  const int* __restrict__ col,
                                                  const float* __restrict__ w,
                                                  const float* __restrict__ g2,
                                                  float* __restrict__ acc2, int E, int n) {
    long long t = (long long)blockIdx.x * 256 + threadIdx.x;
    int e = (int)(t >> 4);
    int j = (int)(t & 15);
    if (e < E) {
        int r = row[e], c = col[e];
        if ((unsigned)r < (unsigned)n && (unsigned)c < (unsigned)n) {
            float v = g2[r * 16 + j] * w[e];
            atomicAdd(&acc2[c * 16 + j], v);
        }
    }
}

// epilogue 2 + fc: out = leaky(dinv*(acc2+g2)+b2) @ Wfc + bfc
__global__ void k_final(const float* __restrict__ g2, const float* __restrict__ acc2,
                        const float* __restrict__ dinv, const float* __restrict__ b2,
                        const float* __restrict__ Wfc, const float* __restrict__ bfc,
                        float* __restrict__ out, int n) {
    int node = blockIdx.x * blockDim.x + threadIdx.x;
    if (node < n) {
        float di = dinv[node];
        float s = 0.f;
#pragma unroll
        for (int j = 0; j < 16; ++j) {
            float v = di * (acc2[node * 16 + j] + g2[node * 16 + j]) + b2[j];
            v = v > 0.f ? v : 0.01f * v;
            s += v * Wfc[j];
        }
        out[node] = s + bfc[0];
    }
}

extern "C" void kernel_launch(void* const* d_in, const int* in_sizes, int n_in,
                              void* d_out, int out_size, void* d_ws, size_t ws_size,
                              hipStream_t stream) {
    const float*    x    = (const float*)d_in[0];
    const unsigned* eidx = (const unsigned*)d_in[1];  // [2,E]; int64 or int32, detected on device
    const float*    ew   = (const float*)d_in[2];
    const float*    W1   = (const float*)d_in[3];
    const float*    b1   = (const float*)d_in[4];
    const float*    W2   = (const float*)d_in[5];
    const float*    b2   = (const float*)d_in[6];
    const float*    Wfc  = (const float*)d_in[7];
    const float*    bfc  = (const float*)d_in[8];
    float* out = (float*)d_out;

    const int N = N_NODES;
    const int E = N_EDGES;

    char* ws = (char*)d_ws;
    int*   flag  = (int*)ws;                            // 4 B
    float* dinv  = (float*)(ws + 4096);                 // N floats (0.4 MB)
    int*   row   = (int*)(ws + (1u  << 20));            // E ints (12.8 MB)
    int*   col   = (int*)(ws + (14u << 20));            // E ints (12.8 MB)
    float* bufA  = (float*)(ws + (27u << 20));          // N*32 floats (12.8 MB)  g1 / g2
    float* bufB  = (float*)(ws + (40u << 20));          // N*32 floats           acc1/h1/acc2

    // --- normalize edge index dtype ---
    k_detect<<<1, 256, 0, stream>>>(eidx, flag);
    k_convert<<<(E + 255) / 256, 256, 0, stream>>>(eidx, flag, row, col, E);

    // --- norm ---
    k_deg_init<<<(N + 255) / 256, 256, 0, stream>>>(dinv, N);
    k_deg_accum<<<(E + 255) / 256, 256, 0, stream>>>(col, ew, dinv, E, N);
    k_dinv<<<(N + 255) / 256, 256, 0, stream>>>(dinv, N);

    // --- layer 1 ---
    k_gemm1<<<(N + 7) / 8, 256, 0, stream>>>(x, W1, dinv, bufA, N);
    hipMemsetAsync(bufB, 0, (size_t)N * 32 * sizeof(float), stream);
    {
        long long threads = (long long)E * 32;
        int blocks = (int)((threads + 255) / 256);
        k_scatter1<<<blocks, 256, 0, stream>>>(row, col, ew, bufA, bufB, E, N);
    }
    k_post1<<<(N * 32 + 255) / 256, 256, 0, stream>>>(bufA, dinv, b1, bufB, N);

    // --- layer 2 ---
    k_gemm2<<<(N * 16 + 255) / 256, 256, 0, stream>>>(bufB, W2, dinv, bufA, N);
    hipMemsetAsync(bufB, 0, (size_t)N * 16 * sizeof(float), stream);
    {
        long long threads = (long long)E * 16;
        int blocks = (int)((threads + 255) / 256);
        k_scatter2<<<blocks, 256, 0, stream>>>(row, col, ew, bufA, bufB, E, N);
    }
    k_final<<<(N + 255) / 256, 256, 0, stream>>>(bufA, bufB, dinv, b2, Wfc, bfc, out, N);
}

// Round 4
// 824.765 us; speedup vs baseline: 1.0539x; 1.0539x over previous
//
#include <hip/hip_runtime.h>
#include <hip/hip_bf16.h>

#define N_NODES 100000
#define N_EDGES 3200000
#define NBLK_SCAN ((N_NODES + 255) / 256)   // 391

// ---------------- edge_index dtype detect ----------------
// Handles either int64 or int32 upload of edge_index. For int64 data
// (values < 2^31) the int32-view odd words are all zero; genuine int32 data
// has random indices there. Graph-capture safe: same work every call.

__global__ void k_detect(const unsigned* __restrict__ w, int* __restrict__ flag) {
    __shared__ unsigned s[256];
    unsigned v = 0;
    for (int t = threadIdx.x; t < 4096; t += 256) v |= w[2 * t + 1];
    s[threadIdx.x] = v;
    __syncthreads();
    for (int off = 128; off > 0; off >>= 1) {
        if (threadIdx.x < (unsigned)off) s[threadIdx.x] |= s[threadIdx.x + off];
        __syncthreads();
    }
    if (threadIdx.x == 0) flag[0] = (s[0] == 0) ? 1 : 0;  // 1 => int64 layout
}

__device__ __forceinline__ int load_col(const unsigned* e, int f, int E, int i) {
    return f ? (int)e[2 * E + 2 * i] : (int)e[E + i];
}
__device__ __forceinline__ int load_row(const unsigned* e, int f, int E, int i) {
    return f ? (int)e[2 * i] : (int)e[i];
}

// ---------------- CSR build: histogram / scan / place ----------------

__global__ void k_hist(const unsigned* __restrict__ eidx, const int* __restrict__ flag,
                       int* __restrict__ cnt, int E, int n) {
    int e = blockIdx.x * blockDim.x + threadIdx.x;
    if (e < E) {
        int c = load_col(eidx, flag[0], E, e);
        if ((unsigned)c < (unsigned)n) atomicAdd(&cnt[c], 1);
    }
}

__global__ void k_scan1(const int* __restrict__ cnt, int* __restrict__ start,
                        int* __restrict__ blksum, int n) {
    __shared__ int s[256];
    int i = blockIdx.x * 256 + threadIdx.x;
    int v = (i < n) ? cnt[i] : 0;
    s[threadIdx.x] = v;
    __syncthreads();
    for (int off = 1; off < 256; off <<= 1) {
        int t = (threadIdx.x >= off) ? s[threadIdx.x - off] : 0;
        __syncthreads();
        s[threadIdx.x] += t;
        __syncthreads();
    }
    if (i < n) start[i] = s[threadIdx.x] - v;          // block-local exclusive
    if (threadIdx.x == 255) blksum[blockIdx.x] = s[255];
}

__global__ void k_scan2(int* __restrict__ blksum, int nblk) {
    __shared__ int s[512];
    int t = threadIdx.x;
    int v = (t < nblk) ? blksum[t] : 0;
    s[t] = v;
    __syncthreads();
    for (int off = 1; off < 512; off <<= 1) {
        int u = (t >= off) ? s[t - off] : 0;
        __syncthreads();
        s[t] += u;
        __syncthreads();
    }
    if (t < nblk) blksum[t] = s[t] - v;                // exclusive block offsets
}

__global__ void k_scan3(int* __restrict__ start, const int* __restrict__ blksum,
                        int* __restrict__ cursor, int n, int E) {
    int i = blockIdx.x * 256 + threadIdx.x;
    if (i < n) {
        int v = start[i] + blksum[blockIdx.x];
        start[i] = v;
        cursor[i] = v;
    }
    if (i == 0) start[n] = E;
}

__global__ void k_place(const unsigned* __restrict__ eidx, const int* __restrict__ flag,
                        const float* __restrict__ ew, int* __restrict__ cursor,
                        int2* __restrict__ erw, int E, int n) {
    int e = blockIdx.x * blockDim.x + threadIdx.x;
    if (e < E) {
        int f = flag[0];
        int r = load_row(eidx, f, E, e);
        int c = load_col(eidx, f, E, e);
        if ((unsigned)r < (unsigned)n && (unsigned)c < (unsigned)n) {
            int p = atomicAdd(&cursor[c], 1);
            erw[p] = make_int2(r, __float_as_int(ew[e]));
        }
    }
}

// dinv[i] = 1/sqrt(1 + sum of incoming weights)
__global__ void k_dinv(const int* __restrict__ start, const int2* __restrict__ erw,
                       float* __restrict__ dinv, int n) {
    int i = blockIdx.x * blockDim.x + threadIdx.x;
    if (i < n) {
        float d = 1.0f;  // self-loop
        int s = start[i], en = start[i + 1];
        for (int e = s; e < en; ++e) d += __int_as_float(erw[e].y);
        dinv[i] = 1.0f / sqrtf(d);
    }
}

// ---------------- layer 1 transform: g1 = dinv * (x @ W1) ----------------
// block = 256 threads = 8 nodes x 32 out-channels. W1 (128x32) in LDS.

__global__ __launch_bounds__(256) void k_gemm1(const float* __restrict__ x,
                                               const float* __restrict__ W1,
                                               const float* __restrict__ dinv,
                                               float* __restrict__ g1, int n) {
    __shared__ float W1s[128 * 32];
    __shared__ float xs[8][128];
    int tid = threadIdx.x;
    for (int i = tid; i < 128 * 32; i += 256) W1s[i] = W1[i];
    int node0 = blockIdx.x * 8;
    for (int i = tid; i < 8 * 128; i += 256) {
        int ln = i >> 7, ii = i & 127;
        int node = node0 + ln;
        xs[ln][ii] = (node < n) ? x[node * 128 + ii] : 0.f;
    }
    __syncthreads();
    int ln = tid >> 5;
    int kk = tid & 31;
    int node = node0 + ln;
    if (node < n) {
        float acc = 0.f;
#pragma unroll
        for (int i = 0; i < 128; ++i) acc += xs[ln][i] * W1s[i * 32 + kk];
        g1[node * 32 + kk] = dinv[node] * acc;
    }
}

// ---------------- layer 1 aggregate (gather, no atomics) ----------------
// one wave per node: lanes = 2 edge-slots x 32 channels.
// h1[c,k] = leaky( dinv[c] * (sum_e w_e*g1[row_e,k] + g1[c,k]) + b1[k] )

__global__ __launch_bounds__(256) void k_agg1(const float* __restrict__ g,
                                              const int* __restrict__ start,
                                              const int2* __restrict__ erw,
                                              const float* __restrict__ dinv,
                                              const float* __restrict__ b1,
                                              float* __restrict__ h, int n) {
    int wid = (blockIdx.x * 256 + threadIdx.x) >> 6;  // node
    int l = threadIdx.x & 63;
    if (wid >= n) return;
    int es = l >> 5;       // 0..1
    int k  = l & 31;       // channel
    int s = start[wid], en = start[wid + 1];
    float acc = 0.f;
    for (int e = s + es; e < en; e += 2) {
        int2 rw = erw[e];
        acc += __int_as_float(rw.y) * g[rw.x * 32 + k];
    }
    acc += __shfl_xor(acc, 32);
    float v = dinv[wid] * (acc + g[wid * 32 + k]) + b1[k];
    v = v > 0.f ? v : 0.01f * v;
    if (l < 32) h[wid * 32 + l] = v;
}

// ---------------- layer 2 transform: g2 = dinv * (h1 @ W2) ----------------

__global__ __launch_bounds__(256) void k_gemm2(const float* __restrict__ h1,
                                               const float* __restrict__ W2,
                                               const float* __restrict__ dinv,
                                               float* __restrict__ g2, int n) {
    __shared__ float W2s[32 * 16];
    int tid = threadIdx.x;
    for (int i = tid; i < 32 * 16; i += 256) W2s[i] = W2[i];
    __syncthreads();
    int t = blockIdx.x * 256 + tid;
    if (t < n * 16) {
        int node = t >> 4, j = t & 15;
        float acc = 0.f;
#pragma unroll
        for (int k = 0; k < 32; ++k) acc += h1[node * 32 + k] * W2s[k * 16 + j];
        g2[t] = dinv[node] * acc;
    }
}

// ---------------- layer 2 aggregate + fc (gather, fused) ----------------
// one wave per node: lanes = 4 edge-slots x 16 channels.
// v_j = leaky(dinv*(agg_j + g2[c,j]) + b2[j]);  out[c] = sum_j v_j*Wfc[j] + bfc

__global__ __launch_bounds__(256) void k_agg2(const float* __restrict__ g2,
                                              const int* __restrict__ start,
                                              const int2* __restrict__ erw,
                                              const float* __restrict__ dinv,
                                              const float* __restrict__ b2,
                                              const float* __restrict__ Wfc,
                                              const float* __restrict__ bfc,
                                              float* __restrict__ out, int n) {
    int wid = (blockIdx.x * 256 + threadIdx.x) >> 6;  // node
    int l = threadIdx.x & 63;
    if (wid >= n) return;
    int es = l >> 4;       // 0..3
    int j  = l & 15;       // channel
    int s = start[wid], en = start[wid + 1];
    float acc = 0.f;
    for (int e = s + es; e < en; e += 4) {
        int2 rw = erw[e];
        acc += __int_as_float(rw.y) * g2[rw.x * 16 + j];
    }
    acc += __shfl_xor(acc, 16);
    acc += __shfl_xor(acc, 32);
    float v = dinv[wid] * (acc + g2[wid * 16 + j]) + b2[j];
    v = v > 0.f ? v : 0.01f * v;
    float sres = v * Wfc[j];
    sres += __shfl_xor(sres, 1);
    sres += __shfl_xor(sres, 2);
    sres += __shfl_xor(sres, 4);
    sres += __shfl_xor(sres, 8);
    if (l == 0) out[wid] = sres + bfc[0];
}

extern "C" void kernel_launch(void* const* d_in, const int* in_sizes, int n_in,
                              void* d_out, int out_size, void* d_ws, size_t ws_size,
                              hipStream_t stream) {
    const float*    x    = (const float*)d_in[0];
    const unsigned* eidx = (const unsigned*)d_in[1];
    const float*    ew   = (const float*)d_in[2];
    const float*    W1   = (const float*)d_in[3];
    const float*    b1   = (const float*)d_in[4];
    const float*    W2   = (const float*)d_in[5];
    const float*    b2   = (const float*)d_in[6];
    const float*    Wfc  = (const float*)d_in[7];
    const float*    bfc  = (const float*)d_in[8];
    float* out = (float*)d_out;

    const int N = N_NODES;
    const int E = N_EDGES;

    char* ws = (char*)d_ws;
    int*   flag   = (int*)ws;                           // 4 B
    int*   cnt    = (int*)(ws + 1024);                  // N ints
    int*   start  = (int*)(ws + 512u * 1024);           // N+1 ints
    int*   cursor = (int*)(ws + 1024u * 1024);          // N ints
    float* dinv   = (float*)(ws + 1536u * 1024);        // N floats
    int*   blksum = (int*)(ws + 1984u * 1024);          // 512 ints
    int2*  erw    = (int2*)(ws + 2048u * 1024);         // E int2 (25.6 MB)
    float* bufA   = (float*)(ws + 28u * 1024 * 1024);   // N*32 floats (g1 / g2)
    float* bufB   = (float*)(ws + 41u * 1024 * 1024);   // N*32 floats (h1)

    // --- detect edge_index dtype ---
    k_detect<<<1, 256, 0, stream>>>(eidx, flag);

    // --- CSR build by target ---
    hipMemsetAsync(cnt, 0, (size_t)N * sizeof(int), stream);
    k_hist<<<(E + 255) / 256, 256, 0, stream>>>(eidx, flag, cnt, E, N);
    k_scan1<<<NBLK_SCAN, 256, 0, stream>>>(cnt, start, blksum, N);
    k_scan2<<<1, 512, 0, stream>>>(blksum, NBLK_SCAN);
    k_scan3<<<NBLK_SCAN, 256, 0, stream>>>(start, blksum, cursor, N, E);
    k_place<<<(E + 255) / 256, 256, 0, stream>>>(eidx, flag, ew, cursor, erw, E, N);
    k_dinv<<<(N + 255) / 256, 256, 0, stream>>>(start, erw, dinv, N);

    // --- layer 1 ---
    k_gemm1<<<(N + 7) / 8, 256, 0, stream>>>(x, W1, dinv, bufA, N);
    {
        int blocks = (int)(((long long)N * 64 + 255) / 256);
        k_agg1<<<blocks, 256, 0, stream>>>(bufA, start, erw, dinv, b1, bufB, N);
    }

    // --- layer 2 (+ fc fused) ---
    k_gemm2<<<(N * 16 + 255) / 256, 256, 0, stream>>>(bufB, W2, dinv, bufA, N);
    {
        int blocks = (int)(((long long)N * 64 + 255) / 256);
        k_agg2<<<blocks, 256, 0, stream>>>(bufA, start, erw, dinv, b2, Wfc, bfc, out, N);
    }
}

// Round 5
// 558.767 us; speedup vs baseline: 1.5556x; 1.4760x over previous
//
#include <hip/hip_runtime.h>

#define N_NODES 100000
#define N_EDGES 3200000
#define BSHIFT 8
#define BSIZE 256
#define NB ((N_NODES + BSIZE - 1) / BSIZE)   // 391 buckets of 256 nodes
#define ROWBITS 17
#define ROWMASK ((1 << ROWBITS) - 1)
#define EB_GRID ((N_EDGES + 4095) / 4096)    // 782 blocks, 4096 edges each

// ---------------- edge_index dtype detect ----------------
// int64 upload: odd int32 words (high words) are all zero. int32 upload:
// those positions hold random indices. Graph-capture safe, same work per call.

__global__ void k_detect(const unsigned* __restrict__ w, int* __restrict__ flag) {
    __shared__ unsigned s[256];
    unsigned v = 0;
    for (int t = threadIdx.x; t < 4096; t += 256) v |= w[2 * t + 1];
    s[threadIdx.x] = v;
    __syncthreads();
    for (int off = 128; off > 0; off >>= 1) {
        if (threadIdx.x < (unsigned)off) s[threadIdx.x] |= s[threadIdx.x + off];
        __syncthreads();
    }
    if (threadIdx.x == 0) flag[0] = (s[0] == 0) ? 1 : 0;  // 1 => int64 layout
}

__device__ __forceinline__ void load_edge(const unsigned* __restrict__ e, int f, int E,
                                          int i, int& r, int& c) {
    if (f) { r = (int)e[2 * i]; c = (int)e[2 * E + 2 * i]; }
    else   { r = (int)e[i];     c = (int)e[E + i]; }
}

// ---------------- bucket counting sort (CSR build) ----------------

__global__ __launch_bounds__(256) void k_bcnt(const unsigned* __restrict__ eidx,
                                              const int* __restrict__ flag,
                                              int* __restrict__ bcnt, int E, int n) {
    __shared__ int lc[NB];
    for (int i = threadIdx.x; i < NB; i += 256) lc[i] = 0;
    __syncthreads();
    int f = flag[0];
    int base = blockIdx.x * 4096;
    for (int i = 0; i < 16; ++i) {
        int e = base + i * 256 + threadIdx.x;
        if (e < E) {
            int r, c;
            load_edge(eidx, f, E, e, r, c);
            if ((unsigned)r < (unsigned)n && (unsigned)c < (unsigned)n)
                atomicAdd(&lc[c >> BSHIFT], 1);
        }
    }
    __syncthreads();
    for (int i = threadIdx.x; i < NB; i += 256)
        if (lc[i]) atomicAdd(&bcnt[i], lc[i]);
}

__global__ __launch_bounds__(512) void k_bscan(const int* __restrict__ bcnt,
                                               int* __restrict__ bbase,
                                               int* __restrict__ gcursor,
                                               int* __restrict__ start) {
    __shared__ int s[512];
    int tid = threadIdx.x;
    int v = (tid < NB) ? bcnt[tid] : 0;
    s[tid] = v;
    __syncthreads();
    for (int o = 1; o < 512; o <<= 1) {
        int t = (tid >= o) ? s[tid - o] : 0;
        __syncthreads();
        s[tid] += t;
        __syncthreads();
    }
    if (tid < NB) {
        int excl = s[tid] - v;
        bbase[tid] = excl;
        gcursor[tid] = excl;
    }
    if (tid == 511) {
        bbase[NB] = s[511];          // total placed edges
        start[N_NODES] = s[511];
    }
}

// pass A: scatter edges into bucket regions, block-aggregated cursors
__global__ __launch_bounds__(256) void k_bucket(const unsigned* __restrict__ eidx,
                                                const int* __restrict__ flag,
                                                const float* __restrict__ ew,
                                                int* __restrict__ gcursor,
                                                int2* __restrict__ bstage, int E, int n) {
    __shared__ int lcnt[NB];
    __shared__ int lbase[NB];
    __shared__ int lcur[NB];
    int tid = threadIdx.x;
    for (int i = tid; i < NB; i += 256) { lcnt[i] = 0; lcur[i] = 0; }
    __syncthreads();
    int f = flag[0];
    int base = blockIdx.x * 4096;
    for (int i = 0; i < 16; ++i) {
        int e = base + i * 256 + tid;
        if (e < E) {
            int r, c;
            load_edge(eidx, f, E, e, r, c);
            if ((unsigned)r < (unsigned)n && (unsigned)c < (unsigned)n)
                atomicAdd(&lcnt[c >> BSHIFT], 1);
        }
    }
    __syncthreads();
    for (int i = tid; i < NB; i += 256)
        lbase[i] = atomicAdd(&gcursor[i], lcnt[i]);
    __syncthreads();
    for (int i = 0; i < 16; ++i) {
        int e = base + i * 256 + tid;
        if (e < E) {
            int r, c;
            load_edge(eidx, f, E, e, r, c);
            if ((unsigned)r < (unsigned)n && (unsigned)c < (unsigned)n) {
                int b = c >> BSHIFT, off = c & (BSIZE - 1);
                int p = lbase[b] + atomicAdd(&lcur[b], 1);
                bstage[p] = make_int2((off << ROWBITS) | r, __float_as_int(ew[e]));
            }
        }
    }
}

// pass B: per-bucket counting sort into final CSR + start[] + dinv[]
__global__ __launch_bounds__(256) void k_passb(const int2* __restrict__ bstage,
                                               const int* __restrict__ bbase,
                                               int* __restrict__ start,
                                               float* __restrict__ dinv,
                                               int2* __restrict__ erw, int n) {
    __shared__ int   cnt[BSIZE];
    __shared__ float wsm[BSIZE];
    __shared__ int   cur[BSIZE];
    int tid = threadIdx.x;
    int b = blockIdx.x;
    int n0 = b << BSHIFT;
    int nn = min(BSIZE, n - n0);
    int bb = bbase[b], be = bbase[b + 1];
    cnt[tid] = 0;
    wsm[tid] = 0.f;
    __syncthreads();
    for (int e = bb + tid; e < be; e += 256) {
        int2 kv = bstage[e];
        int off = kv.x >> ROWBITS;
        atomicAdd(&cnt[off], 1);
        atomicAdd(&wsm[off], __int_as_float(kv.y));
    }
    __syncthreads();
    int v = cnt[tid];
    for (int o = 1; o < 256; o <<= 1) {       // inclusive scan
        int t = (tid >= o) ? cnt[tid - o] : 0;
        __syncthreads();
        cnt[tid] += t;
        __syncthreads();
    }
    int excl = cnt[tid] - v;
    if (tid < nn) {
        start[n0 + tid] = bb + excl;
        dinv[n0 + tid] = 1.0f / sqrtf(1.0f + wsm[tid]);
    }
    cur[tid] = excl;
    __syncthreads();
    for (int e = bb + tid; e < be; e += 256) {
        int2 kv = bstage[e];
        int off = kv.x >> ROWBITS;
        int p = bb + atomicAdd(&cur[off], 1);
        erw[p] = make_int2(kv.x & ROWMASK, kv.y);
    }
}

// ---------------- layer 1 transform: g1 = dinv * (x @ W1) ----------------

__global__ __launch_bounds__(256) void k_gemm1(const float* __restrict__ x,
                                               const float* __restrict__ W1,
                                               const float* __restrict__ dinv,
                                               float* __restrict__ g1, int n) {
    __shared__ float W1s[128 * 32];
    __shared__ float xs[8][128];
    int tid = threadIdx.x;
    for (int i = tid; i < 128 * 32; i += 256) W1s[i] = W1[i];
    int node0 = blockIdx.x * 8;
    for (int i = tid; i < 8 * 128; i += 256) {
        int ln = i >> 7, ii = i & 127;
        int node = node0 + ln;
        xs[ln][ii] = (node < n) ? x[node * 128 + ii] : 0.f;
    }
    __syncthreads();
    int ln = tid >> 5;
    int kk = tid & 31;
    int node = node0 + ln;
    if (node < n) {
        float acc = 0.f;
#pragma unroll
        for (int i = 0; i < 128; ++i) acc += xs[ln][i] * W1s[i * 32 + kk];
        g1[node * 32 + kk] = dinv[node] * acc;
    }
}

// ---------------- layer 1 aggregate (gather) ----------------
// one wave per node: 2 edge-slots x 32 channels.

__global__ __launch_bounds__(256) void k_agg1(const float* __restrict__ g,
                                              const int* __restrict__ start,
                                              const int2* __restrict__ erw,
                                              const float* __restrict__ dinv,
                                              const float* __restrict__ b1,
                                              float* __restrict__ h, int n) {
    int wid = (blockIdx.x * 256 + threadIdx.x) >> 6;
    int l = threadIdx.x & 63;
    if (wid >= n) return;
    int es = l >> 5;
    int k  = l & 31;
    int s = start[wid], en = start[wid + 1];
    float acc = 0.f;
    for (int e = s + es; e < en; e += 2) {
        int2 rw = erw[e];
        acc += __int_as_float(rw.y) * g[rw.x * 32 + k];
    }
    acc += __shfl_xor(acc, 32);
    float v = dinv[wid] * (acc + g[wid * 32 + k]) + b1[k];
    v = v > 0.f ? v : 0.01f * v;
    if (l < 32) h[wid * 32 + l] = v;
}

// ---------------- layer 2 transform: g2 = dinv * (h1 @ W2) ----------------

__global__ __launch_bounds__(256) void k_gemm2(const float* __restrict__ h1,
                                               const float* __restrict__ W2,
                                               const float* __restrict__ dinv,
                                               float* __restrict__ g2, int n) {
    __shared__ float W2s[32 * 16];
    int tid = threadIdx.x;
    for (int i = tid; i < 32 * 16; i += 256) W2s[i] = W2[i];
    __syncthreads();
    int t = blockIdx.x * 256 + tid;
    if (t < n * 16) {
        int node = t >> 4, j = t & 15;
        float acc = 0.f;
#pragma unroll
        for (int k = 0; k < 32; ++k) acc += h1[node * 32 + k] * W2s[k * 16 + j];
        g2[t] = dinv[node] * acc;
    }
}

// ---------------- layer 2 aggregate + fc (fused) ----------------
// one wave per node: 4 edge-slots x 16 channels.

__global__ __launch_bounds__(256) void k_agg2(const float* __restrict__ g2,
                                              const int* __restrict__ start,
                                              const int2* __restrict__ erw,
                                              const float* __restrict__ dinv,
                                              const float* __restrict__ b2,
                                              const float* __restrict__ Wfc,
                                              const float* __restrict__ bfc,
                                              float* __restrict__ out, int n) {
    int wid = (blockIdx.x * 256 + threadIdx.x) >> 6;
    int l = threadIdx.x & 63;
    if (wid >= n) return;
    int es = l >> 4;
    int j  = l & 15;
    int s = start[wid], en = start[wid + 1];
    float acc = 0.f;
    for (int e = s + es; e < en; e += 4) {
        int2 rw = erw[e];
        acc += __int_as_float(rw.y) * g2[rw.x * 16 + j];
    }
    acc += __shfl_xor(acc, 16);
    acc += __shfl_xor(acc, 32);
    float v = dinv[wid] * (acc + g2[wid * 16 + j]) + b2[j];
    v = v > 0.f ? v : 0.01f * v;
    float sres = v * Wfc[j];
    sres += __shfl_xor(sres, 1);
    sres += __shfl_xor(sres, 2);
    sres += __shfl_xor(sres, 4);
    sres += __shfl_xor(sres, 8);
    if (l == 0) out[wid] = sres + bfc[0];
}

extern "C" void kernel_launch(void* const* d_in, const int* in_sizes, int n_in,
                              void* d_out, int out_size, void* d_ws, size_t ws_size,
                              hipStream_t stream) {
    const float*    x    = (const float*)d_in[0];
    const unsigned* eidx = (const unsigned*)d_in[1];
    const float*    ew   = (const float*)d_in[2];
    const float*    W1   = (const float*)d_in[3];
    const float*    b1   = (const float*)d_in[4];
    const float*    W2   = (const float*)d_in[5];
    const float*    b2   = (const float*)d_in[6];
    const float*    Wfc  = (const float*)d_in[7];
    const float*    bfc  = (const float*)d_in[8];
    float* out = (float*)d_out;

    const int N = N_NODES;
    const int E = N_EDGES;

    char* ws = (char*)d_ws;
    int*   flag    = (int*)ws;                            // 4 B
    int*   bcnt    = (int*)(ws + 4096);                   // NB ints
    int*   bbase   = (int*)(ws + 8192);                   // NB+1 ints
    int*   gcursor = (int*)(ws + 16384);                  // NB ints
    int*   start   = (int*)(ws + 65536);                  // N+1 ints (400 KB)
    float* dinv    = (float*)(ws + 512u * 1024);          // N floats
    float* bufA    = (float*)(ws + 1u  * 1024 * 1024);    // N*32 floats (g1/g2) — aliases bstage
    float* bufB    = (float*)(ws + 14u * 1024 * 1024);    // N*32 floats (h1)    — aliases bstage
    int2*  bstage  = (int2*)(ws + 1u  * 1024 * 1024);     // E int2 (25.6 MB), dead after k_passb
    int2*  erw     = (int2*)(ws + 27u * 1024 * 1024);     // E int2 (25.6 MB)

    // --- detect edge_index dtype ---
    k_detect<<<1, 256, 0, stream>>>(eidx, flag);

    // --- CSR build via bucketed counting sort ---
    hipMemsetAsync(bcnt, 0, (size_t)NB * sizeof(int), stream);
    k_bcnt<<<EB_GRID, 256, 0, stream>>>(eidx, flag, bcnt, E, N);
    k_bscan<<<1, 512, 0, stream>>>(bcnt, bbase, gcursor, start);
    k_bucket<<<EB_GRID, 256, 0, stream>>>(eidx, flag, ew, gcursor, bstage, E, N);
    k_passb<<<NB, 256, 0, stream>>>(bstage, bbase, start, dinv, erw, N);

    // --- layer 1 ---
    k_gemm1<<<(N + 7) / 8, 256, 0, stream>>>(x, W1, dinv, bufA, N);
    {
        int blocks = (int)(((long long)N * 64 + 255) / 256);
        k_agg1<<<blocks, 256, 0, stream>>>(bufA, start, erw, dinv, b1, bufB, N);
    }

    // --- layer 2 (+ fc fused) ---
    k_gemm2<<<(N * 16 + 255) / 256, 256, 0, stream>>>(bufB, W2, dinv, bufA, N);
    {
        int blocks = (int)(((long long)N * 64 + 255) / 256);
        k_agg2<<<blocks, 256, 0, stream>>>(bufA, start, erw, dinv, b2, Wfc, bfc, out, N);
    }
}

// Round 6
// 426.241 us; speedup vs baseline: 2.0393x; 1.3109x over previous
//
#include <hip/hip_runtime.h>
#include <hip/hip_fp16.h>

#define N_NODES 100000
#define N_EDGES 3200000
#define BSHIFT 8
#define BSIZE 256
#define NB ((N_NODES + BSIZE - 1) / BSIZE)   // 391 buckets of 256 nodes
#define ROWBITS 17
#define ROWMASK ((1 << ROWBITS) - 1)
#define EB_GRID ((N_EDGES + 4095) / 4096)    // 782 blocks, 4096 edges each

// ---------------- edge_index dtype detect ----------------

__global__ void k_detect(const unsigned* __restrict__ w, int* __restrict__ flag) {
    __shared__ unsigned s[256];
    unsigned v = 0;
    for (int t = threadIdx.x; t < 4096; t += 256) v |= w[2 * t + 1];
    s[threadIdx.x] = v;
    __syncthreads();
    for (int off = 128; off > 0; off >>= 1) {
        if (threadIdx.x < (unsigned)off) s[threadIdx.x] |= s[threadIdx.x + off];
        __syncthreads();
    }
    if (threadIdx.x == 0) flag[0] = (s[0] == 0) ? 1 : 0;  // 1 => int64 layout
}

__device__ __forceinline__ void load_edge(const unsigned* __restrict__ e, int f, int E,
                                          int i, int& r, int& c) {
    if (f) { r = (int)e[2 * i]; c = (int)e[2 * E + 2 * i]; }
    else   { r = (int)e[i];     c = (int)e[E + i]; }
}

// ---------------- bucket counting sort (CSR build) ----------------

__global__ __launch_bounds__(256) void k_bcnt(const unsigned* __restrict__ eidx,
                                              const int* __restrict__ flag,
                                              int* __restrict__ bcnt, int E, int n) {
    __shared__ int lc[NB];
    for (int i = threadIdx.x; i < NB; i += 256) lc[i] = 0;
    __syncthreads();
    int f = flag[0];
    int base = blockIdx.x * 4096;
    for (int i = 0; i < 16; ++i) {
        int e = base + i * 256 + threadIdx.x;
        if (e < E) {
            int r, c;
            load_edge(eidx, f, E, e, r, c);
            if ((unsigned)r < (unsigned)n && (unsigned)c < (unsigned)n)
                atomicAdd(&lc[c >> BSHIFT], 1);
        }
    }
    __syncthreads();
    for (int i = threadIdx.x; i < NB; i += 256)
        if (lc[i]) atomicAdd(&bcnt[i], lc[i]);
}

__global__ __launch_bounds__(512) void k_bscan(const int* __restrict__ bcnt,
                                               int* __restrict__ bbase,
                                               int* __restrict__ gcursor,
                                               int* __restrict__ start) {
    __shared__ int s[512];
    int tid = threadIdx.x;
    int v = (tid < NB) ? bcnt[tid] : 0;
    s[tid] = v;
    __syncthreads();
    for (int o = 1; o < 512; o <<= 1) {
        int t = (tid >= o) ? s[tid - o] : 0;
        __syncthreads();
        s[tid] += t;
        __syncthreads();
    }
    if (tid < NB) {
        int excl = s[tid] - v;
        bbase[tid] = excl;
        gcursor[tid] = excl;
    }
    if (tid == 511) {
        bbase[NB] = s[511];
        start[N_NODES] = s[511];
    }
}

// pass A: scatter edges into bucket regions; edges register-cached (1 read pass)
__global__ __launch_bounds__(256) void k_bucket(const unsigned* __restrict__ eidx,
                                                const int* __restrict__ flag,
                                                const float* __restrict__ ew,
                                                int* __restrict__ gcursor,
                                                int2* __restrict__ bstage, int E, int n) {
    __shared__ int lcnt[NB];
    __shared__ int lbase[NB];
    __shared__ int lcur[NB];
    int tid = threadIdx.x;
    for (int i = tid; i < NB; i += 256) { lcnt[i] = 0; lcur[i] = 0; }
    __syncthreads();
    int f = flag[0];
    int base = blockIdx.x * 4096;
    int rr[16], cc[16];
    float wwv[16];
#pragma unroll
    for (int i = 0; i < 16; ++i) {
        int e = base + i * 256 + tid;
        rr[i] = -1; cc[i] = 0; wwv[i] = 0.f;
        if (e < E) {
            int r, c;
            load_edge(eidx, f, E, e, r, c);
            if ((unsigned)r < (unsigned)n && (unsigned)c < (unsigned)n) {
                rr[i] = r; cc[i] = c; wwv[i] = ew[e];
            }
        }
    }
#pragma unroll
    for (int i = 0; i < 16; ++i)
        if (rr[i] >= 0) atomicAdd(&lcnt[cc[i] >> BSHIFT], 1);
    __syncthreads();
    for (int i = tid; i < NB; i += 256)
        lbase[i] = atomicAdd(&gcursor[i], lcnt[i]);
    __syncthreads();
#pragma unroll
    for (int i = 0; i < 16; ++i) {
        if (rr[i] >= 0) {
            int b = cc[i] >> BSHIFT, off = cc[i] & (BSIZE - 1);
            int p = lbase[b] + atomicAdd(&lcur[b], 1);
            bstage[p] = make_int2((off << ROWBITS) | rr[i], __float_as_int(wwv[i]));
        }
    }
}

// pass B: per-bucket counting sort into final CSR + start[] + dinv[]
__global__ __launch_bounds__(256) void k_passb(const int2* __restrict__ bstage,
                                               const int* __restrict__ bbase,
                                               int* __restrict__ start,
                                               float* __restrict__ dinv,
                                               int2* __restrict__ erw, int n) {
    __shared__ int   cnt[BSIZE];
    __shared__ float wsm[BSIZE];
    __shared__ int   cur[BSIZE];
    int tid = threadIdx.x;
    int b = blockIdx.x;
    int n0 = b << BSHIFT;
    int nn = min(BSIZE, n - n0);
    int bb = bbase[b], be = bbase[b + 1];
    cnt[tid] = 0;
    wsm[tid] = 0.f;
    __syncthreads();
    for (int e = bb + tid; e < be; e += 256) {
        int2 kv = bstage[e];
        int off = kv.x >> ROWBITS;
        atomicAdd(&cnt[off], 1);
        atomicAdd(&wsm[off], __int_as_float(kv.y));
    }
    __syncthreads();
    int v = cnt[tid];
    for (int o = 1; o < 256; o <<= 1) {
        int t = (tid >= o) ? cnt[tid - o] : 0;
        __syncthreads();
        cnt[tid] += t;
        __syncthreads();
    }
    int excl = cnt[tid] - v;
    if (tid < nn) {
        start[n0 + tid] = bb + excl;
        dinv[n0 + tid] = 1.0f / sqrtf(1.0f + wsm[tid]);
    }
    cur[tid] = excl;
    __syncthreads();
    for (int e = bb + tid; e < be; e += 256) {
        int2 kv = bstage[e];
        int off = kv.x >> ROWBITS;
        int p = bb + atomicAdd(&cur[off], 1);
        erw[p] = make_int2(kv.x & ROWMASK, kv.y);
    }
}

// ---------------- layer 1 transform: g1 = fp16(dinv * (x @ W1)) ----------------

__global__ __launch_bounds__(256) void k_gemm1(const float* __restrict__ x,
                                               const float* __restrict__ W1,
                                               const float* __restrict__ dinv,
                                               __half* __restrict__ g1, int n) {
    __shared__ float W1s[128 * 32];
    __shared__ float xs[8][128];
    int tid = threadIdx.x;
    for (int i = tid; i < 128 * 32; i += 256) W1s[i] = W1[i];
    int node0 = blockIdx.x * 8;
    for (int i = tid; i < 8 * 128; i += 256) {
        int ln = i >> 7, ii = i & 127;
        int node = node0 + ln;
        xs[ln][ii] = (node < n) ? x[node * 128 + ii] : 0.f;
    }
    __syncthreads();
    int ln = tid >> 5;
    int kk = tid & 31;
    int node = node0 + ln;
    if (node < n) {
        float acc = 0.f;
#pragma unroll
        for (int i = 0; i < 128; ++i) acc += xs[ln][i] * W1s[i * 32 + kk];
        g1[node * 32 + kk] = __float2half(dinv[node] * acc);
    }
}

// ---------------- layer 1 aggregate (gather, fp16 payload) ----------------
// one wave per node: 8 edge-slots x 8 lanes x 4 fp16 channels (8 B loads).

__global__ __launch_bounds__(256) void k_agg1(const __half* __restrict__ g,
                                              const int* __restrict__ start,
                                              const int2* __restrict__ erw,
                                              const float* __restrict__ dinv,
                                              const float* __restrict__ b1,
                                              float* __restrict__ h, int n) {
    int wid = (blockIdx.x * 256 + threadIdx.x) >> 6;
    int l = threadIdx.x & 63;
    if (wid >= n) return;
    int slot = l >> 3;       // 0..7
    int cg   = l & 7;        // channels 4*cg..4*cg+3
    int s = start[wid], en = start[wid + 1];
    float4 acc = make_float4(0.f, 0.f, 0.f, 0.f);
    for (int e0 = s; e0 < en; e0 += 8) {
        int e = e0 + slot;
        if (e < en) {
            int2 rw = erw[e];
            float w = __int_as_float(rw.y);
            float2 raw = *reinterpret_cast<const float2*>(g + ((size_t)rw.x << 5) + (cg << 2));
            __half2 h01 = *reinterpret_cast<const __half2*>(&raw.x);
            __half2 h23 = *reinterpret_cast<const __half2*>(&raw.y);
            float2 f01 = __half22float2(h01), f23 = __half22float2(h23);
            acc.x += w * f01.x; acc.y += w * f01.y;
            acc.z += w * f23.x; acc.w += w * f23.y;
        }
    }
#pragma unroll
    for (int m = 8; m <= 32; m <<= 1) {
        acc.x += __shfl_xor(acc.x, m);
        acc.y += __shfl_xor(acc.y, m);
        acc.z += __shfl_xor(acc.z, m);
        acc.w += __shfl_xor(acc.w, m);
    }
    if (slot == 0) {
        float2 raw = *reinterpret_cast<const float2*>(g + ((size_t)wid << 5) + (cg << 2));
        __half2 h01 = *reinterpret_cast<const __half2*>(&raw.x);
        __half2 h23 = *reinterpret_cast<const __half2*>(&raw.y);
        float2 f01 = __half22float2(h01), f23 = __half22float2(h23);
        float di = dinv[wid];
        float4 b = *reinterpret_cast<const float4*>(b1 + (cg << 2));
        float4 v;
        v.x = di * (acc.x + f01.x) + b.x;
        v.y = di * (acc.y + f01.y) + b.y;
        v.z = di * (acc.z + f23.x) + b.z;
        v.w = di * (acc.w + f23.y) + b.w;
        v.x = v.x > 0.f ? v.x : 0.01f * v.x;
        v.y = v.y > 0.f ? v.y : 0.01f * v.y;
        v.z = v.z > 0.f ? v.z : 0.01f * v.z;
        v.w = v.w > 0.f ? v.w : 0.01f * v.w;
        *reinterpret_cast<float4*>(h + ((size_t)wid << 5) + (cg << 2)) = v;
    }
}

// ---------------- layer 2 transform: g2 = fp16(dinv * (h1 @ W2)) ----------------

__global__ __launch_bounds__(256) void k_gemm2(const float* __restrict__ h1,
                                               const float* __restrict__ W2,
                                               const float* __restrict__ dinv,
                                               __half* __restrict__ g2, int n) {
    __shared__ float W2s[32 * 16];
    int tid = threadIdx.x;
    for (int i = tid; i < 32 * 16; i += 256) W2s[i] = W2[i];
    __syncthreads();
    int t = blockIdx.x * 256 + tid;
    if (t < n * 16) {
        int node = t >> 4, j = t & 15;
        float acc = 0.f;
#pragma unroll
        for (int k = 0; k < 32; ++k) acc += h1[node * 32 + k] * W2s[k * 16 + j];
        g2[t] = __float2half(dinv[node] * acc);
    }
}

// ---------------- layer 2 aggregate + fc (fused, fp16 payload) ----------------
// one wave per node: 16 edge-slots x 4 lanes x 4 fp16 channels.

__global__ __launch_bounds__(256) void k_agg2(const __half* __restrict__ g2,
                                              const int* __restrict__ start,
                                              const int2* __restrict__ erw,
                                              const float* __restrict__ dinv,
                                              const float* __restrict__ b2,
                                              const float* __restrict__ Wfc,
                                              const float* __restrict__ bfc,
                                              float* __restrict__ out, int n) {
    int wid = (blockIdx.x * 256 + threadIdx.x) >> 6;
    int l = threadIdx.x & 63;
    if (wid >= n) return;
    int slot = l >> 2;       // 0..15
    int cg   = l & 3;        // channels 4*cg..4*cg+3
    int s = start[wid], en = start[wid + 1];
    float4 acc = make_float4(0.f, 0.f, 0.f, 0.f);
    for (int e0 = s; e0 < en; e0 += 16) {
        int e = e0 + slot;
        if (e < en) {
            int2 rw = erw[e];
            float w = __int_as_float(rw.y);
            float2 raw = *reinterpret_cast<const float2*>(g2 + ((size_t)rw.x << 4) + (cg << 2));
            __half2 h01 = *reinterpret_cast<const __half2*>(&raw.x);
            __half2 h23 = *reinterpret_cast<const __half2*>(&raw.y);
            float2 f01 = __half22float2(h01), f23 = __half22float2(h23);
            acc.x += w * f01.x; acc.y += w * f01.y;
            acc.z += w * f23.x; acc.w += w * f23.y;
        }
    }
#pragma unroll
    for (int m = 4; m <= 32; m <<= 1) {
        acc.x += __shfl_xor(acc.x, m);
        acc.y += __shfl_xor(acc.y, m);
        acc.z += __shfl_xor(acc.z, m);
        acc.w += __shfl_xor(acc.w, m);
    }
    // epilogue on all lanes (values replicated across slots)
    float2 raw = *reinterpret_cast<const float2*>(g2 + ((size_t)wid << 4) + (cg << 2));
    __half2 h01 = *reinterpret_cast<const __half2*>(&raw.x);
    __half2 h23 = *reinterpret_cast<const __half2*>(&raw.y);
    float2 f01 = __half22float2(h01), f23 = __half22float2(h23);
    float di = dinv[wid];
    float4 b = *reinterpret_cast<const float4*>(b2 + (cg << 2));
    float4 wf = *reinterpret_cast<const float4*>(Wfc + (cg << 2));
    float4 v;
    v.x = di * (acc.x + f01.x) + b.x;
    v.y = di * (acc.y + f01.y) + b.y;
    v.z = di * (acc.z + f23.x) + b.z;
    v.w = di * (acc.w + f23.y) + b.w;
    v.x = v.x > 0.f ? v.x : 0.01f * v.x;
    v.y = v.y > 0.f ? v.y : 0.01f * v.y;
    v.z = v.z > 0.f ? v.z : 0.01f * v.z;
    v.w = v.w > 0.f ? v.w : 0.01f * v.w;
    float p = v.x * wf.x + v.y * wf.y + v.z * wf.z + v.w * wf.w;
    p += __shfl_xor(p, 1);
    p += __shfl_xor(p, 2);
    if (l == 0) out[wid] = p + bfc[0];
}

extern "C" void kernel_launch(void* const* d_in, const int* in_sizes, int n_in,
                              void* d_out, int out_size, void* d_ws, size_t ws_size,
                              hipStream_t stream) {
    const float*    x    = (const float*)d_in[0];
    const unsigned* eidx = (const unsigned*)d_in[1];
    const float*    ew   = (const float*)d_in[2];
    const float*    W1   = (const float*)d_in[3];
    const float*    b1   = (const float*)d_in[4];
    const float*    W2   = (const float*)d_in[5];
    const float*    b2   = (const float*)d_in[6];
    const float*    Wfc  = (const float*)d_in[7];
    const float*    bfc  = (const float*)d_in[8];
    float* out = (float*)d_out;

    const int N = N_NODES;
    const int E = N_EDGES;

    char* ws = (char*)d_ws;
    int*    flag    = (int*)ws;                            // 4 B
    int*    bcnt    = (int*)(ws + 4096);                   // NB ints
    int*    bbase   = (int*)(ws + 8192);                   // NB+1 ints
    int*    gcursor = (int*)(ws + 16384);                  // NB ints
    int*    start   = (int*)(ws + 65536);                  // N+1 ints (400 KB)
    float*  dinv    = (float*)(ws + 512u * 1024);          // N floats
    int2*   erw     = (int2*)(ws + 1u  * 1024 * 1024);     // E int2 (25.6 MB), live all session
    int2*   bstage  = (int2*)(ws + 27u * 1024 * 1024);     // E int2 (25.6 MB), dead after k_passb
    __half* g1h     = (__half*)(ws + 27u * 1024 * 1024);   // N*32 half (6.4 MB)  — aliases bstage
    float*  h1      = (float*)(ws + 34u * 1024 * 1024);    // N*32 float (12.8 MB) — aliases bstage
    __half* g2h     = (__half*)(ws + 47u * 1024 * 1024);   // N*16 half (3.2 MB)

    // --- detect edge_index dtype ---
    k_detect<<<1, 256, 0, stream>>>(eidx, flag);

    // --- CSR build via bucketed counting sort ---
    hipMemsetAsync(bcnt, 0, (size_t)NB * sizeof(int), stream);
    k_bcnt<<<EB_GRID, 256, 0, stream>>>(eidx, flag, bcnt, E, N);
    k_bscan<<<1, 512, 0, stream>>>(bcnt, bbase, gcursor, start);
    k_bucket<<<EB_GRID, 256, 0, stream>>>(eidx, flag, ew, gcursor, bstage, E, N);
    k_passb<<<NB, 256, 0, stream>>>(bstage, bbase, start, dinv, erw, N);

    // --- layer 1 ---
    k_gemm1<<<(N + 7) / 8, 256, 0, stream>>>(x, W1, dinv, g1h, N);
    {
        int blocks = (int)(((long long)N * 64 + 255) / 256);
        k_agg1<<<blocks, 256, 0, stream>>>(g1h, start, erw, dinv, b1, h1, N);
    }

    // --- layer 2 (+ fc fused) ---
    k_gemm2<<<(N * 16 + 255) / 256, 256, 0, stream>>>(h1, W2, dinv, g2h, N);
    {
        int blocks = (int)(((long long)N * 64 + 255) / 256);
        k_agg2<<<blocks, 256, 0, stream>>>(g2h, start, erw, dinv, b2, Wfc, bfc, out, N);
    }
}

// Round 7
// 373.212 us; speedup vs baseline: 2.3291x; 1.1421x over previous
//
#include <hip/hip_runtime.h>
#include <hip/hip_fp16.h>

#define N_NODES 100000
#define N_EDGES 3200000
#define BSHIFT 7
#define BSIZE 128
#define NB ((N_NODES + BSIZE - 1) / BSIZE)   // 782 buckets of 128 nodes
#define CAP 4736                              // mean 4096 + 10 sigma, clamp-guarded
#define ROWBITS 17
#define ROWMASK ((1 << ROWBITS) - 1)
#define EB2 ((N_EDGES + 2047) / 2048)        // 1563 blocks, 2048 edges each

// ---------------- edge_index dtype detect ----------------

__global__ void k_detect(const unsigned* __restrict__ w, int* __restrict__ flag) {
    __shared__ unsigned s[256];
    unsigned v = 0;
    for (int t = threadIdx.x; t < 4096; t += 256) v |= w[2 * t + 1];
    s[threadIdx.x] = v;
    __syncthreads();
    for (int off = 128; off > 0; off >>= 1) {
        if (threadIdx.x < (unsigned)off) s[threadIdx.x] |= s[threadIdx.x + off];
        __syncthreads();
    }
    if (threadIdx.x == 0) flag[0] = (s[0] == 0) ? 1 : 0;  // 1 => int64 layout
}

__device__ __forceinline__ void load_edge(const unsigned* __restrict__ e, int f, int E,
                                          int i, int& r, int& c) {
    if (f) { r = (int)e[2 * i]; c = (int)e[2 * E + 2 * i]; }
    else   { r = (int)e[i];     c = (int)e[E + i]; }
}

// ---------------- single-pass bucket scatter (padded regions) ----------------

__global__ __launch_bounds__(256) void k_scatter(const unsigned* __restrict__ eidx,
                                                 const int* __restrict__ flag,
                                                 const float* __restrict__ ew,
                                                 int* __restrict__ gcursor,
                                                 int2* __restrict__ bstage, int E, int n) {
    __shared__ int lcnt[NB];
    __shared__ int lbase[NB];
    __shared__ int lcur[NB];
    int tid = threadIdx.x;
    for (int i = tid; i < NB; i += 256) { lcnt[i] = 0; lcur[i] = 0; }
    __syncthreads();
    int f = flag[0];
    int base = blockIdx.x * 2048;
    int rr[8], cc[8];
    float wv[8];
#pragma unroll
    for (int i = 0; i < 8; ++i) {
        int e = base + i * 256 + tid;
        rr[i] = -1; cc[i] = 0; wv[i] = 0.f;
        if (e < E) {
            int r, c;
            load_edge(eidx, f, E, e, r, c);
            if ((unsigned)r < (unsigned)n && (unsigned)c < (unsigned)n) {
                rr[i] = r; cc[i] = c; wv[i] = ew[e];
            }
        }
    }
#pragma unroll
    for (int i = 0; i < 8; ++i)
        if (rr[i] >= 0) atomicAdd(&lcnt[cc[i] >> BSHIFT], 1);
    __syncthreads();
    for (int i = tid; i < NB; i += 256)
        if (lcnt[i]) lbase[i] = atomicAdd(&gcursor[i], lcnt[i]);
    __syncthreads();
#pragma unroll
    for (int i = 0; i < 8; ++i) {
        if (rr[i] >= 0) {
            int b = cc[i] >> BSHIFT, off = cc[i] & (BSIZE - 1);
            int pos = lbase[b] + atomicAdd(&lcur[b], 1);
            if (pos < CAP)
                bstage[(size_t)b * CAP + pos] =
                    make_int2((off << ROWBITS) | rr[i], __float_as_int(wv[i]));
        }
    }
}

// ---------------- per-bucket counting sort, in-place via LDS staging ----------------

__global__ __launch_bounds__(256) void k_passb(const int* __restrict__ gcursor,
                                               int2* __restrict__ erw,   // == bstage
                                               int* __restrict__ start,
                                               int* __restrict__ end,
                                               float* __restrict__ dinv, int n) {
    __shared__ int2  se[CAP];        // 37.9 KB
    __shared__ int   cnt[256];       // upper 128 stay zero for the scan
    __shared__ float wsm[BSIZE];
    __shared__ int   cur[BSIZE];
    int tid = threadIdx.x;
    int b = blockIdx.x;
    int n0 = b << BSHIFT;
    int nn = min(BSIZE, n - n0);
    size_t bb = (size_t)b * CAP;
    int cntE = min(gcursor[b], CAP);
    cnt[tid] = 0;
    if (tid < BSIZE) wsm[tid] = 0.f;
    __syncthreads();
    for (int e = tid; e < cntE; e += 256) {
        int2 kv = erw[bb + e];
        se[e] = kv;
        int off = kv.x >> ROWBITS;
        atomicAdd(&cnt[off], 1);
        atomicAdd(&wsm[off], __int_as_float(kv.y));
    }
    __syncthreads();
    int v = cnt[tid];
    for (int o = 1; o < 256; o <<= 1) {
        int t = (tid >= o) ? cnt[tid - o] : 0;
        __syncthreads();
        cnt[tid] += t;
        __syncthreads();
    }
    int excl = cnt[tid] - v;
    if (tid < nn) {
        start[n0 + tid] = (int)bb + excl;
        end[n0 + tid]   = (int)bb + excl + v;
        dinv[n0 + tid]  = 1.0f / sqrtf(1.0f + wsm[tid]);
    }
    if (tid < BSIZE) cur[tid] = excl;
    __syncthreads();
    for (int e = tid; e < cntE; e += 256) {
        int2 kv = se[e];
        int off = kv.x >> ROWBITS;
        int p = atomicAdd(&cur[off], 1);
        erw[bb + p] = make_int2(kv.x & ROWMASK, kv.y);
    }
}

// ---------------- layer 1 transform: g1 = fp16(dinv * (x @ W1)) ----------------

__global__ __launch_bounds__(256) void k_gemm1(const float* __restrict__ x,
                                               const float* __restrict__ W1,
                                               const float* __restrict__ dinv,
                                               __half* __restrict__ g1, int n) {
    __shared__ float W1s[128 * 32];
    __shared__ float xs[8][128];
    int tid = threadIdx.x;
    for (int i = tid; i < 1024; i += 256)
        *reinterpret_cast<float4*>(W1s + 4 * i) = reinterpret_cast<const float4*>(W1)[i];
    int node0 = blockIdx.x * 8;
    {
        int ln = tid >> 5, ii = tid & 31;
        int node = node0 + ln;
        float4 vv = make_float4(0.f, 0.f, 0.f, 0.f);
        if (node < n) vv = reinterpret_cast<const float4*>(x)[node * 32 + ii];
        *reinterpret_cast<float4*>(&xs[ln][4 * ii]) = vv;
    }
    __syncthreads();
    int ln = tid >> 5;
    int kk = tid & 31;
    int node = node0 + ln;
    if (node < n) {
        float acc = 0.f;
#pragma unroll
        for (int i = 0; i < 128; ++i) acc += xs[ln][i] * W1s[i * 32 + kk];
        g1[node * 32 + kk] = __float2half(dinv[node] * acc);
    }
}

// ---------------- layer 1 aggregate (gather, fp16 payload) ----------------

__global__ __launch_bounds__(256) void k_agg1(const __half* __restrict__ g,
                                              const int* __restrict__ start,
                                              const int* __restrict__ end,
                                              const int2* __restrict__ erw,
                                              const float* __restrict__ dinv,
                                              const float* __restrict__ b1,
                                              float* __restrict__ h, int n) {
    int wid = (blockIdx.x * 256 + threadIdx.x) >> 6;
    int l = threadIdx.x & 63;
    if (wid >= n) return;
    int slot = l >> 3;       // 0..7
    int cg   = l & 7;        // channels 4*cg..4*cg+3
    int s = start[wid], en = end[wid];
    float4 acc = make_float4(0.f, 0.f, 0.f, 0.f);
    for (int e0 = s; e0 < en; e0 += 8) {
        int e = e0 + slot;
        if (e < en) {
            int2 rw = erw[e];
            float w = __int_as_float(rw.y);
            float2 raw = *reinterpret_cast<const float2*>(g + ((size_t)rw.x << 5) + (cg << 2));
            __half2 h01 = *reinterpret_cast<const __half2*>(&raw.x);
            __half2 h23 = *reinterpret_cast<const __half2*>(&raw.y);
            float2 f01 = __half22float2(h01), f23 = __half22float2(h23);
            acc.x += w * f01.x; acc.y += w * f01.y;
            acc.z += w * f23.x; acc.w += w * f23.y;
        }
    }
#pragma unroll
    for (int m = 8; m <= 32; m <<= 1) {
        acc.x += __shfl_xor(acc.x, m);
        acc.y += __shfl_xor(acc.y, m);
        acc.z += __shfl_xor(acc.z, m);
        acc.w += __shfl_xor(acc.w, m);
    }
    if (slot == 0) {
        float2 raw = *reinterpret_cast<const float2*>(g + ((size_t)wid << 5) + (cg << 2));
        __half2 h01 = *reinterpret_cast<const __half2*>(&raw.x);
        __half2 h23 = *reinterpret_cast<const __half2*>(&raw.y);
        float2 f01 = __half22float2(h01), f23 = __half22float2(h23);
        float di = dinv[wid];
        float4 b = *reinterpret_cast<const float4*>(b1 + (cg << 2));
        float4 v;
        v.x = di * (acc.x + f01.x) + b.x;
        v.y = di * (acc.y + f01.y) + b.y;
        v.z = di * (acc.z + f23.x) + b.z;
        v.w = di * (acc.w + f23.y) + b.w;
        v.x = v.x > 0.f ? v.x : 0.01f * v.x;
        v.y = v.y > 0.f ? v.y : 0.01f * v.y;
        v.z = v.z > 0.f ? v.z : 0.01f * v.z;
        v.w = v.w > 0.f ? v.w : 0.01f * v.w;
        *reinterpret_cast<float4*>(h + ((size_t)wid << 5) + (cg << 2)) = v;
    }
}

// ---------------- layer 2 transform: g2 = fp16(dinv * (h1 @ W2)) ----------------

__global__ __launch_bounds__(256) void k_gemm2(const float* __restrict__ h1,
                                               const float* __restrict__ W2,
                                               const float* __restrict__ dinv,
                                               __half* __restrict__ g2, int n) {
    __shared__ float W2s[32 * 16];
    int tid = threadIdx.x;
    for (int i = tid; i < 32 * 16; i += 256) W2s[i] = W2[i];
    __syncthreads();
    int t = blockIdx.x * 256 + tid;
    if (t < n * 16) {
        int node = t >> 4, j = t & 15;
        float acc = 0.f;
#pragma unroll
        for (int k = 0; k < 32; ++k) acc += h1[node * 32 + k] * W2s[k * 16 + j];
        g2[t] = __float2half(dinv[node] * acc);
    }
}

// ---------------- layer 2 aggregate + fc (fused, fp16 payload) ----------------

__global__ __launch_bounds__(256) void k_agg2(const __half* __restrict__ g2,
                                              const int* __restrict__ start,
                                              const int* __restrict__ end,
                                              const int2* __restrict__ erw,
                                              const float* __restrict__ dinv,
                                              const float* __restrict__ b2,
                                              const float* __restrict__ Wfc,
                                              const float* __restrict__ bfc,
                                              float* __restrict__ out, int n) {
    int wid = (blockIdx.x * 256 + threadIdx.x) >> 6;
    int l = threadIdx.x & 63;
    if (wid >= n) return;
    int slot = l >> 2;       // 0..15
    int cg   = l & 3;        // channels 4*cg..4*cg+3
    int s = start[wid], en = end[wid];
    float4 acc = make_float4(0.f, 0.f, 0.f, 0.f);
    for (int e0 = s; e0 < en; e0 += 16) {
        int e = e0 + slot;
        if (e < en) {
            int2 rw = erw[e];
            float w = __int_as_float(rw.y);
            float2 raw = *reinterpret_cast<const float2*>(g2 + ((size_t)rw.x << 4) + (cg << 2));
            __half2 h01 = *reinterpret_cast<const __half2*>(&raw.x);
            __half2 h23 = *reinterpret_cast<const __half2*>(&raw.y);
            float2 f01 = __half22float2(h01), f23 = __half22float2(h23);
            acc.x += w * f01.x; acc.y += w * f01.y;
            acc.z += w * f23.x; acc.w += w * f23.y;
        }
    }
#pragma unroll
    for (int m = 4; m <= 32; m <<= 1) {
        acc.x += __shfl_xor(acc.x, m);
        acc.y += __shfl_xor(acc.y, m);
        acc.z += __shfl_xor(acc.z, m);
        acc.w += __shfl_xor(acc.w, m);
    }
    float2 raw = *reinterpret_cast<const float2*>(g2 + ((size_t)wid << 4) + (cg << 2));
    __half2 h01 = *reinterpret_cast<const __half2*>(&raw.x);
    __half2 h23 = *reinterpret_cast<const __half2*>(&raw.y);
    float2 f01 = __half22float2(h01), f23 = __half22float2(h23);
    float di = dinv[wid];
    float4 b = *reinterpret_cast<const float4*>(b2 + (cg << 2));
    float4 wf = *reinterpret_cast<const float4*>(Wfc + (cg << 2));
    float4 v;
    v.x = di * (acc.x + f01.x) + b.x;
    v.y = di * (acc.y + f01.y) + b.y;
    v.z = di * (acc.z + f23.x) + b.z;
    v.w = di * (acc.w + f23.y) + b.w;
    v.x = v.x > 0.f ? v.x : 0.01f * v.x;
    v.y = v.y > 0.f ? v.y : 0.01f * v.y;
    v.z = v.z > 0.f ? v.z : 0.01f * v.z;
    v.w = v.w > 0.f ? v.w : 0.01f * v.w;
    float p = v.x * wf.x + v.y * wf.y + v.z * wf.z + v.w * wf.w;
    p += __shfl_xor(p, 1);
    p += __shfl_xor(p, 2);
    if (l == 0) out[wid] = p + bfc[0];
}

extern "C" void kernel_launch(void* const* d_in, const int* in_sizes, int n_in,
                              void* d_out, int out_size, void* d_ws, size_t ws_size,
                              hipStream_t stream) {
    const float*    x    = (const float*)d_in[0];
    const unsigned* eidx = (const unsigned*)d_in[1];
    const float*    ew   = (const float*)d_in[2];
    const float*    W1   = (const float*)d_in[3];
    const float*    b1   = (const float*)d_in[4];
    const float*    W2   = (const float*)d_in[5];
    const float*    b2   = (const float*)d_in[6];
    const float*    Wfc  = (const float*)d_in[7];
    const float*    bfc  = (const float*)d_in[8];
    float* out = (float*)d_out;

    const int N = N_NODES;
    const int E = N_EDGES;

    char* ws = (char*)d_ws;
    int*    flag    = (int*)ws;                            // 4 B
    int*    gcursor = (int*)(ws + 4096);                   // NB ints (3.1 KB)
    int*    start   = (int*)(ws + 64u * 1024);             // N ints (400 KB)
    int*    end     = (int*)(ws + 512u * 1024);            // N ints (400 KB)
    float*  dinv    = (float*)(ws + 1024u * 1024);         // N floats (400 KB)
    int2*   erw     = (int2*)(ws + 2u * 1024 * 1024);      // NB*CAP int2 (29.6 MB), == bstage
    __half* g1h     = (__half*)(ws + 32u * 1024 * 1024);   // N*32 half (6.4 MB)
    float*  h1      = (float*)(ws + 39u * 1024 * 1024);    // N*32 float (12.8 MB)
    __half* g2h     = (__half*)(ws + 52u * 1024 * 1024);   // N*16 half (3.2 MB)

    k_detect<<<1, 256, 0, stream>>>(eidx, flag);

    // --- CSR build: padded-bucket scatter + in-place per-bucket sort ---
    hipMemsetAsync(gcursor, 0, (size_t)NB * sizeof(int), stream);
    k_scatter<<<EB2, 256, 0, stream>>>(eidx, flag, ew, gcursor, erw, E, N);
    k_passb<<<NB, 256, 0, stream>>>(gcursor, erw, start, end, dinv, N);

    // --- layer 1 ---
    k_gemm1<<<(N + 7) / 8, 256, 0, stream>>>(x, W1, dinv, g1h, N);
    {
        int blocks = (int)(((long long)N * 64 + 255) / 256);
        k_agg1<<<blocks, 256, 0, stream>>>(g1h, start, end, erw, dinv, b1, h1, N);
    }

    // --- layer 2 (+ fc fused) ---
    k_gemm2<<<(N * 16 + 255) / 256, 256, 0, stream>>>(h1, W2, dinv, g2h, N);
    {
        int blocks = (int)(((long long)N * 64 + 255) / 256);
        k_agg2<<<blocks, 256, 0, stream>>>(g2h, start, end, erw, dinv, b2, Wfc, bfc, out, N);
    }
}